// Round 2
// baseline (7159.237 us; speedup 1.0000x reference)
//
#include <hip/hip_runtime.h>
#include <math.h>

#define BB 8
#define CC 36
#define HH 256
#define WW 256
#define EE 6
#define TD 32
#define HID 72
// ws layout (floats): [0,288) pool_avg[B][C]; [288,576) pool_max[B][C]; [576,624) gates[B][E]
#define WS_GATES (BB*CC*2)

// ---------------- Kernel 1: avg+max pool over H,W per (b,c) ----------------
__global__ __launch_bounds__(256) void pool_kernel(const float* __restrict__ x,
                                                   float* __restrict__ ws) {
  const int bc = blockIdx.x;                    // 0..287
  const float* p = x + (size_t)bc * (HH * WW);
  float s = 0.f, m = -INFINITY;
  for (int i = threadIdx.x; i < (HH * WW) / 4; i += 256) {
    float4 v = ((const float4*)p)[i];
    s += v.x + v.y + v.z + v.w;
    m = fmaxf(m, fmaxf(fmaxf(v.x, v.y), fmaxf(v.z, v.w)));
  }
  for (int off = 32; off; off >>= 1) {
    s += __shfl_down(s, off);
    m = fmaxf(m, __shfl_down(m, off));
  }
  __shared__ float ss[4], sm[4];
  int wid = threadIdx.x >> 6, lane = threadIdx.x & 63;
  if (lane == 0) { ss[wid] = s; sm[wid] = m; }
  __syncthreads();
  if (threadIdx.x == 0) {
    float S = ss[0] + ss[1] + ss[2] + ss[3];
    float M = fmaxf(fmaxf(sm[0], sm[1]), fmaxf(sm[2], sm[3]));
    ws[bc] = S * (1.f / (HH * WW));
    ws[BB * CC + bc] = M;
  }
}

// ---------------- Kernel 2: gating MLP + top-2 softmax gates + loss ----------------
__global__ void gate_kernel(const float* __restrict__ time,
                            const float* __restrict__ time_w,
                            const float* __restrict__ time_b,
                            const float* __restrict__ w1, const float* __restrict__ b1,
                            const float* __restrict__ w2, const float* __restrict__ b2,
                            float* __restrict__ ws, float* __restrict__ loss_out) {
  __shared__ float v[BB * HID];
  __shared__ float h[BB * HID];
  __shared__ float logits[BB * EE];
  const int t = threadIdx.x;
  const float* avg = ws;
  const float* mx = ws + BB * CC;
  for (int i = t; i < BB * HID; i += blockDim.x) {
    int b = i / HID, c = i % HID;
    float base = (c < CC) ? avg[b * CC + c] : mx[b * CC + (c - CC)];
    float acc = time_b[c];
    for (int k = 0; k < TD; k++) acc += time[b * TD + k] * time_w[k * HID + c];
    v[i] = base + acc;
  }
  __syncthreads();
  for (int i = t; i < BB * HID; i += blockDim.x) {
    int b = i / HID, c = i % HID;
    float acc = b1[c];
    for (int k = 0; k < HID; k++) acc += v[b * HID + k] * w1[k * HID + c];
    h[i] = acc > 0.f ? acc : 0.01f * acc;  // LeakyReLU(0.01)
  }
  __syncthreads();
  for (int i = t; i < BB * EE; i += blockDim.x) {
    int b = i / EE, e = i % EE;
    float acc = b2[e];
    for (int k = 0; k < HID; k++) acc += h[b * HID + k] * w2[k * EE + e];
    logits[i] = acc;
  }
  __syncthreads();
  if (t == 0) {
    float imp[EE], ld[EE];
    for (int e = 0; e < EE; e++) { imp[e] = 0.f; ld[e] = 0.f; }
    for (int b = 0; b < BB; b++) {
      int i1 = -1, i2 = -1;
      float v1 = -1e30f, v2 = -1e30f;
      for (int e = 0; e < EE; e++) {
        float lv = logits[b * EE + e];
        if (lv > v1) { v2 = v1; i2 = i1; v1 = lv; i1 = e; }
        else if (lv > v2) { v2 = lv; i2 = e; }
      }
      float e2 = expf(v2 - v1);
      float g1 = 1.f / (1.f + e2), g2 = e2 / (1.f + e2);
      for (int e = 0; e < EE; e++) ws[WS_GATES + b * EE + e] = 0.f;
      ws[WS_GATES + b * EE + i1] = g1;
      ws[WS_GATES + b * EE + i2] = g2;
      imp[i1] += g1; imp[i2] += g2;
      ld[i1] += 1.f; ld[i2] += 1.f;
    }
    float loss = 0.f;
    {
      float m = 0.f; for (int e = 0; e < EE; e++) m += imp[e]; m /= EE;
      float var = 0.f; for (int e = 0; e < EE; e++) { float d = imp[e] - m; var += d * d; }
      var /= (EE - 1);
      loss += var / (m * m + 1e-10f);
      m = 0.f; for (int e = 0; e < EE; e++) m += ld[e]; m /= EE;
      var = 0.f; for (int e = 0; e < EE; e++) { float d = ld[e] - m; var += d * d; }
      var /= (EE - 1);
      loss += var / (m * m + 1e-10f);
    }
    loss_out[0] = 0.01f * loss;
  }
}

// ---------------- Kernel 3: fused conv1 + GELU + conv2, gate-weighted ----------------
// One block = one (b, 8x8 output tile). Loops experts; skips gate==0 (uniform branch).
// xs: x tile + halo2 (36 x 12 x 12); ts: intermediate (72 x 10 x 10). Both LDS.
// NOTE: intermediate positions OUTSIDE the image must be exactly 0 (the
// reference zero-pads the GELU(conv1) tensor for conv2) — mask them.
__global__ __launch_bounds__(256) void conv_kernel(const float* __restrict__ x,
                                                   const float* __restrict__ w1g,
                                                   const float* __restrict__ w2g,
                                                   const float* __restrict__ ws,
                                                   float* __restrict__ y) {
  __shared__ float xs[CC * 12 * 12];
  __shared__ float ts[HID * 10 * 10];
  const int tile = blockIdx.x;            // 0..1023
  const int b = blockIdx.y;               // 0..7
  const int tx0 = (tile & 31) * 8;
  const int ty0 = (tile >> 5) * 8;
  const int tid = threadIdx.x;
  const size_t xb = (size_t)b * (CC * HH * WW);

  for (int i = tid; i < CC * 144; i += 256) {
    int c = i / 144, r = i % 144;
    int ly = r / 12, lx = r % 12;
    int gy = ty0 - 2 + ly, gx = tx0 - 2 + lx;
    float val = 0.f;
    if ((unsigned)gy < (unsigned)HH && (unsigned)gx < (unsigned)WW)
      val = x[xb + ((size_t)c * HH + gy) * WW + gx];
    xs[i] = val;
  }

  float yacc[3][4];
  #pragma unroll
  for (int a = 0; a < 3; a++)
    #pragma unroll
    for (int j = 0; j < 4; j++) yacc[a][j] = 0.f;

  __syncthreads();

  const float* gates = ws + WS_GATES + b * EE;
  for (int e = 0; e < EE; e++) {
    const float g = gates[e];
    if (g == 0.f) continue;   // uniform per block

    // conv1 (36 -> 72) + exact GELU into ts. 4 co per thread for LDS reuse.
    const float* w1 = w1g + (size_t)e * (HID * CC * 9);
    for (int k = 0; k < 8; k++) {
      int i = tid + k * 256;
      if (i >= 1800) break;            // 18 co-groups * 100 pixels
      int grp = i / 100, p = i % 100;
      int ry = p / 10, rx = p % 10;
      // global position of this intermediate pixel; outside image -> exact 0
      int gy = ty0 - 1 + ry, gx = tx0 - 1 + rx;
      bool valid = ((unsigned)gy < (unsigned)HH) && ((unsigned)gx < (unsigned)WW);
      int co = grp * 4;
      float a0 = 0.f, a1 = 0.f, a2 = 0.f, a3 = 0.f;
      const float* wp = w1 + (size_t)co * (CC * 9);
      for (int ci = 0; ci < CC; ci++) {
        const float* xbase = xs + ci * 144 + ry * 12 + rx;
        const float* wb = wp + ci * 9;
        #pragma unroll
        for (int dy = 0; dy < 3; dy++) {
          #pragma unroll
          for (int dx = 0; dx < 3; dx++) {
            float xv = xbase[dy * 12 + dx];
            int wi = dy * 3 + dx;
            a0 += xv * wb[wi];
            a1 += xv * wb[324 + wi];
            a2 += xv * wb[648 + wi];
            a3 += xv * wb[972 + wi];
          }
        }
      }
      ts[(co + 0) * 100 + p] = valid ? 0.5f * a0 * (1.f + erff(a0 * 0.70710678118f)) : 0.f;
      ts[(co + 1) * 100 + p] = valid ? 0.5f * a1 * (1.f + erff(a1 * 0.70710678118f)) : 0.f;
      ts[(co + 2) * 100 + p] = valid ? 0.5f * a2 * (1.f + erff(a2 * 0.70710678118f)) : 0.f;
      ts[(co + 3) * 100 + p] = valid ? 0.5f * a3 * (1.f + erff(a3 * 0.70710678118f)) : 0.f;
    }
    __syncthreads();

    // conv2 (72 -> 36), accumulate gate-weighted into registers.
    const float* w2 = w2g + (size_t)e * (CC * HID * 9);
    for (int k = 0; k < 3; k++) {
      int i = tid + k * 256;
      if (i >= 576) break;             // 9 co-groups * 64 pixels
      int grp = i / 64, p = i % 64;
      int oy = p / 8, ox = p % 8;
      int co = grp * 4;
      float a0 = 0.f, a1 = 0.f, a2 = 0.f, a3 = 0.f;
      const float* wp = w2 + (size_t)co * (HID * 9);
      for (int ci = 0; ci < HID; ci++) {
        const float* tbase = ts + ci * 100 + oy * 10 + ox;
        const float* wb = wp + ci * 9;
        #pragma unroll
        for (int dy = 0; dy < 3; dy++) {
          #pragma unroll
          for (int dx = 0; dx < 3; dx++) {
            float tv = tbase[dy * 10 + dx];
            int wi = dy * 3 + dx;
            a0 += tv * wb[wi];
            a1 += tv * wb[648 + wi];
            a2 += tv * wb[1296 + wi];
            a3 += tv * wb[1944 + wi];
          }
        }
      }
      yacc[k][0] += g * a0;
      yacc[k][1] += g * a1;
      yacc[k][2] += g * a2;
      yacc[k][3] += g * a3;
    }
    __syncthreads();   // ts reused by next active expert
  }

  for (int k = 0; k < 3; k++) {
    int i = tid + k * 256;
    if (i >= 576) break;
    int grp = i / 64, p = i % 64;
    int oy = p / 8, ox = p % 8;
    int co = grp * 4;
    size_t base = xb + ((size_t)co * HH + (ty0 + oy)) * WW + (tx0 + ox);
    y[base] = yacc[k][0];
    y[base + (size_t)HH * WW] = yacc[k][1];
    y[base + 2 * (size_t)HH * WW] = yacc[k][2];
    y[base + 3 * (size_t)HH * WW] = yacc[k][3];
  }
}

extern "C" void kernel_launch(void* const* d_in, const int* in_sizes, int n_in,
                              void* d_out, int out_size, void* d_ws, size_t ws_size,
                              hipStream_t stream) {
  const float* x      = (const float*)d_in[0];
  const float* time   = (const float*)d_in[1];
  const float* time_w = (const float*)d_in[2];
  const float* time_b = (const float*)d_in[3];
  const float* gw1    = (const float*)d_in[4];
  const float* gb1    = (const float*)d_in[5];
  const float* gw2    = (const float*)d_in[6];
  const float* gb2    = (const float*)d_in[7];
  const float* w1     = (const float*)d_in[8];
  const float* w2     = (const float*)d_in[9];
  float* out = (float*)d_out;
  float* ws  = (float*)d_ws;

  hipLaunchKernelGGL(pool_kernel, dim3(BB * CC), dim3(256), 0, stream, x, ws);
  hipLaunchKernelGGL(gate_kernel, dim3(1), dim3(128), 0, stream,
                     time, time_w, time_b, gw1, gb1, gw2, gb2,
                     ws, out + (size_t)(out_size - 1));
  hipLaunchKernelGGL(conv_kernel, dim3(1024, BB), dim3(256), 0, stream,
                     x, w1, w2, ws, out);
}

// Round 3
// 696.745 us; speedup vs baseline: 10.2753x; 10.2753x over previous
//
#include <hip/hip_runtime.h>
#include <math.h>

#define BB 8
#define CCH 36
#define HH 256
#define WW 256
#define EE 6
#define TDIM 32
#define HID 72
// ws layout: floats [0,288) avg; [288,576) max; [576,624) gates.
// bytes: wt1 (bf16) at 4096, size 6*3*80*128*2 = 368640; wt2 at 372736, size 6*3*48*224*2 = 387072.
#define WS_GATES (BB*CCH*2)
#define WT1_OFF 4096
#define WT2_OFF (4096 + 368640)

typedef __attribute__((ext_vector_type(8))) short bf16x8;
typedef __attribute__((ext_vector_type(4))) float f32x4;
typedef __attribute__((ext_vector_type(4))) short short4v;
typedef __attribute__((ext_vector_type(4))) int int4v;

static __device__ __forceinline__ unsigned short f2bf(float f) {
  union { float f; unsigned u; } v; v.f = f;
  unsigned r = v.u + 0x7FFF + ((v.u >> 16) & 1);
  return (unsigned short)(r >> 16);
}
static __device__ __forceinline__ float gelu_exact(float a) {
  return 0.5f * a * (1.f + erff(a * 0.70710678118654752f));
}

// ---------------- Kernel 1: avg+max pool ----------------
__global__ __launch_bounds__(256) void pool_kernel(const float* __restrict__ x,
                                                   float* __restrict__ ws) {
  const int bc = blockIdx.x;
  const float* p = x + (size_t)bc * (HH * WW);
  float s = 0.f, m = -INFINITY;
  for (int i = threadIdx.x; i < (HH * WW) / 4; i += 256) {
    float4 v = ((const float4*)p)[i];
    s += v.x + v.y + v.z + v.w;
    m = fmaxf(m, fmaxf(fmaxf(v.x, v.y), fmaxf(v.z, v.w)));
  }
  for (int off = 32; off; off >>= 1) {
    s += __shfl_down(s, off);
    m = fmaxf(m, __shfl_down(m, off));
  }
  __shared__ float ss[4], sm[4];
  int wid = threadIdx.x >> 6, lane = threadIdx.x & 63;
  if (lane == 0) { ss[wid] = s; sm[wid] = m; }
  __syncthreads();
  if (threadIdx.x == 0) {
    float S = ss[0] + ss[1] + ss[2] + ss[3];
    float M = fmaxf(fmaxf(sm[0], sm[1]), fmaxf(sm[2], sm[3]));
    ws[bc] = S * (1.f / (HH * WW));
    ws[BB * CCH + bc] = M;
  }
}

// ---------------- Kernel 2: gating MLP + top-2 + loss ----------------
__global__ void gate_kernel(const float* __restrict__ time,
                            const float* __restrict__ time_w,
                            const float* __restrict__ time_b,
                            const float* __restrict__ w1, const float* __restrict__ b1,
                            const float* __restrict__ w2, const float* __restrict__ b2,
                            float* __restrict__ ws, float* __restrict__ loss_out) {
  __shared__ float v[BB * HID];
  __shared__ float h[BB * HID];
  __shared__ float logits[BB * EE];
  const int t = threadIdx.x;
  const float* avg = ws;
  const float* mx = ws + BB * CCH;
  for (int i = t; i < BB * HID; i += blockDim.x) {
    int b = i / HID, c = i % HID;
    float base = (c < CCH) ? avg[b * CCH + c] : mx[b * CCH + (c - CCH)];
    float acc = time_b[c];
    for (int k = 0; k < TDIM; k++) acc += time[b * TDIM + k] * time_w[k * HID + c];
    v[i] = base + acc;
  }
  __syncthreads();
  for (int i = t; i < BB * HID; i += blockDim.x) {
    int b = i / HID, c = i % HID;
    float acc = b1[c];
    for (int k = 0; k < HID; k++) acc += v[b * HID + k] * w1[k * HID + c];
    h[i] = acc > 0.f ? acc : 0.01f * acc;
  }
  __syncthreads();
  for (int i = t; i < BB * EE; i += blockDim.x) {
    int b = i / EE, e = i % EE;
    float acc = b2[e];
    for (int k = 0; k < HID; k++) acc += h[b * HID + k] * w2[k * EE + e];
    logits[i] = acc;
  }
  __syncthreads();
  if (t == 0) {
    float imp[EE], ld[EE];
    for (int e = 0; e < EE; e++) { imp[e] = 0.f; ld[e] = 0.f; }
    for (int b = 0; b < BB; b++) {
      int i1 = -1, i2 = -1;
      float v1 = -1e30f, v2 = -1e30f;
      for (int e = 0; e < EE; e++) {
        float lv = logits[b * EE + e];
        if (lv > v1) { v2 = v1; i2 = i1; v1 = lv; i1 = e; }
        else if (lv > v2) { v2 = lv; i2 = e; }
      }
      float e2 = expf(v2 - v1);
      float g1 = 1.f / (1.f + e2), g2 = e2 / (1.f + e2);
      for (int e = 0; e < EE; e++) ws[WS_GATES + b * EE + e] = 0.f;
      ws[WS_GATES + b * EE + i1] = g1;
      ws[WS_GATES + b * EE + i2] = g2;
      imp[i1] += g1; imp[i2] += g2;
      ld[i1] += 1.f; ld[i2] += 1.f;
    }
    float loss = 0.f;
    {
      float m = 0.f; for (int e = 0; e < EE; e++) m += imp[e]; m /= EE;
      float var = 0.f; for (int e = 0; e < EE; e++) { float d = imp[e] - m; var += d * d; }
      var /= (EE - 1);
      loss += var / (m * m + 1e-10f);
      m = 0.f; for (int e = 0; e < EE; e++) m += ld[e]; m /= EE;
      var = 0.f; for (int e = 0; e < EE; e++) { float d = ld[e] - m; var += d * d; }
      var /= (EE - 1);
      loss += var / (m * m + 1e-10f);
    }
    loss_out[0] = 0.01f * loss;
  }
}

// ---------------- Kernel 2.5: weight transform to [e][dx][co][k] bf16 ----------------
// conv1: k = dy*40 + ci  (K=120 used, padded 128), co padded 72->80
// conv2: k = dy*72 + ci  (K=216 used, padded 224), co padded 36->48
__global__ __launch_bounds__(256) void wxform_kernel(const float* __restrict__ w1,
                                                     const float* __restrict__ w2,
                                                     unsigned short* __restrict__ wt1,
                                                     unsigned short* __restrict__ wt2) {
  int i = blockIdx.x * 256 + threadIdx.x;
  const int n1 = EE * 3 * 80 * 128;
  if (i < n1) {
    int k = i & 127;
    int t = i >> 7;
    int co = t % 80; t /= 80;
    int dx = t % 3;  int e = t / 3;
    int dy = k / 40, ci = k - dy * 40;
    float v = 0.f;
    if (co < HID && dy < 3 && ci < CCH)
      v = w1[((((size_t)e * HID + co) * CCH + ci) * 3 + dy) * 3 + dx];
    wt1[i] = f2bf(v);
  }
  const int n2 = EE * 3 * 48 * 224;
  if (i < n2) {
    int k = i % 224;
    int t = i / 224;
    int co = t % 48; t /= 48;
    int dx = t % 3;  int e = t / 3;
    int dy = k / 72, ci = k - dy * 72;
    float v = 0.f;
    if (co < CCH && dy < 3)
      v = w2[((((size_t)e * CCH + co) * HID + ci) * 3 + dy) * 3 + dx];
    wt2[i] = f2bf(v);
  }
}

// ---------------- Kernel 3: fused MFMA conv1+GELU+conv2 ----------------
// Tile: 32 wide x 2 tall outputs. x tile: [6][36][40] bf16 (ch-minor, ci pad 40).
// T tile: [4][34][72] bf16 (ch-minor). Weights staged per-dx into wlds with
// XOR swizzle byte ^= ((co&7)<<4) (pow2 row strides 256B/512B).
#define XRR 6
#define XCC 36
#define CIP 40
#define TRR 4
#define TCC 34
#define LDS_XS 0
#define LDS_TS 17280
#define LDS_W  36864
__global__ __launch_bounds__(256, 2) void conv_kernel(
    const float* __restrict__ x,
    const unsigned short* __restrict__ wt1,
    const unsigned short* __restrict__ wt2,
    const float* __restrict__ wsg,
    float* __restrict__ y) {
  __shared__ __align__(16) char lds[61440];
  char* xsB = lds + LDS_XS;   // 17280 B
  char* tsB = lds + LDS_TS;   // 19584 B
  char* wB  = lds + LDS_W;    // 24576 B

  const int tid = threadIdx.x;
  const int w = tid >> 6;
  const int lane = tid & 63;
  const int l15 = lane & 15;
  const int kl = lane >> 4;
  const int swz = (l15 & 7) << 4;
  const int tileId = blockIdx.x;
  const int b = blockIdx.y;
  const int tx0 = (tileId & 7) * 32;
  const int ty0 = (tileId >> 3) * 2;
  const size_t xbase = (size_t)b * (CCH * HH * WW);

  // ---- stage x tile (f32 -> bf16, ch-minor) ----
  for (int i = tid; i < XRR * XCC * CIP; i += 256) {
    int xc = i % XCC;
    int t2 = i / XCC;
    int xr = t2 % XRR;
    int ci = t2 / XRR;                       // 0..39
    int gy = ty0 - 2 + xr, gx = tx0 - 2 + xc;
    float v = 0.f;
    if (ci < CCH && (unsigned)gy < (unsigned)HH && (unsigned)gx < (unsigned)WW)
      v = x[xbase + ((size_t)ci << 16) + (size_t)(gy * WW + gx)];
    *(unsigned short*)(xsB + 2 * ((xr * XCC + xc) * CIP + ci)) = f2bf(v);
  }

  // ---- per-lane K-chunk tables ----
  int dy1[4], ci1[4], g1[4];
#pragma unroll
  for (int kc = 0; kc < 4; kc++) {
    int k0 = kc * 32 + kl * 8;
    int d = (k0 >= 80) ? 2 : (k0 >= 40 ? 1 : 0);
    dy1[kc] = d; ci1[kc] = k0 - 40 * d; g1[kc] = (k0 < 120) ? 1 : 0;
  }
  int dy2[7], ci2[7], g2[7];
#pragma unroll
  for (int kc = 0; kc < 7; kc++) {
    int k0 = kc * 32 + kl * 8;
    int d = (k0 >= 144) ? 2 : (k0 >= 72 ? 1 : 0);
    dy2[kc] = d; ci2[kc] = k0 - 72 * d; g2[kc] = (k0 < 216) ? 1 : 0;
  }

  // ---- conv1 pixel coords (T grid, 4x34 = 136 px, 9 N-tiles; wave w owns nt = w, w+4, w+8) ----
  int truA[3], tcA[3], vimg[3], pst[3];
#pragma unroll
  for (int i = 0; i < 3; i++) {
    int p = (w + 4 * i) * 16 + l15;
    int pr = p / 34;
    int tc = p - pr * 34;
    truA[i] = pr < 3 ? pr : 3;
    tcA[i] = tc;
    int gy = ty0 - 1 + pr, gx = tx0 - 1 + tc;
    pst[i] = (pr < 4) ? 1 : 0;
    vimg[i] = (pr < 4 && (unsigned)gy < (unsigned)HH && (unsigned)gx < (unsigned)WW) ? 1 : 0;
  }
  // conv2 pixel coords (2x32 = 64 px, wave w owns N-tile w)
  const int p2 = w * 16 + l15;
  const int or2 = p2 >> 5, oc2 = p2 & 31;

  f32x4 yacc[3];
#pragma unroll
  for (int mt = 0; mt < 3; mt++) yacc[mt] = (f32x4){0.f, 0.f, 0.f, 0.f};

  __syncthreads();

  for (int e = 0; e < EE; e++) {
    const float gv = wsg[b * EE + e];
    if (gv == 0.f) continue;

    // ================= conv1 =================
    f32x4 acc[3][5];
#pragma unroll
    for (int i = 0; i < 3; i++)
#pragma unroll
      for (int mt = 0; mt < 5; mt++) acc[i][mt] = (f32x4){0.f, 0.f, 0.f, 0.f};

    const unsigned short* w1e = wt1 + (size_t)e * (3 * 80 * 128);
    for (int dx = 0; dx < 3; dx++) {
      __syncthreads();
      {  // stage wt1[e][dx] -> wlds [80][128] with XOR swizzle (1280 granules)
        const char* src = (const char*)(w1e + dx * 80 * 128);
#pragma unroll
        for (int j = 0; j < 5; j++) {
          int g = tid + j * 256;
          int dst = (g * 16) ^ (((g >> 4) & 7) << 4);
          *(int4v*)(wB + dst) = *(const int4v*)(src + g * 16);
        }
      }
      __syncthreads();
#pragma unroll
      for (int kc = 0; kc < 4; kc++) {
        bf16x8 av[5];
#pragma unroll
        for (int mt = 0; mt < 5; mt++)
          av[mt] = *(const bf16x8*)(wB + ((mt * 4096 + l15 * 256 + kl * 16 + kc * 64) ^ swz));
#pragma unroll
        for (int i = 0; i < 3; i++) {
          if (i < 2 || w == 0) {
            int ba = g1[kc] ? (((truA[i] + dy1[kc]) * XCC + tcA[i] + dx) * (CIP * 2) + ci1[kc] * 2) : 0;
            bf16x8 bv = *(const bf16x8*)(xsB + ba);
#pragma unroll
            for (int mt = 0; mt < 5; mt++)
              acc[i][mt] = __builtin_amdgcn_mfma_f32_16x16x32_bf16(av[mt], bv, acc[i][mt], 0, 0, 0);
          }
        }
      }
    }

    // ---- GELU + store T (bf16, ch-minor, zero outside image) ----
#pragma unroll
    for (int i = 0; i < 3; i++) {
      if (i < 2 || w == 0) {
#pragma unroll
        for (int mt = 0; mt < 5; mt++) {
          int co0 = mt * 16 + kl * 4;
          if (co0 < HID && pst[i]) {
            short4v pk;
            float v0 = vimg[i] ? gelu_exact(acc[i][mt].x) : 0.f;
            float v1 = vimg[i] ? gelu_exact(acc[i][mt].y) : 0.f;
            float v2 = vimg[i] ? gelu_exact(acc[i][mt].z) : 0.f;
            float v3 = vimg[i] ? gelu_exact(acc[i][mt].w) : 0.f;
            pk.x = (short)f2bf(v0); pk.y = (short)f2bf(v1);
            pk.z = (short)f2bf(v2); pk.w = (short)f2bf(v3);
            *(short4v*)(tsB + ((truA[i] * TCC + tcA[i]) * HID + co0) * 2) = pk;
          }
        }
      }
    }

    // ================= conv2 =================
    f32x4 acc2[3];
#pragma unroll
    for (int mt = 0; mt < 3; mt++) acc2[mt] = (f32x4){0.f, 0.f, 0.f, 0.f};

    const unsigned short* w2e = wt2 + (size_t)e * (3 * 48 * 224);
    for (int dx = 0; dx < 3; dx++) {
      __syncthreads();
      {  // stage wt2[e][dx] -> wlds [48][256-pad] with XOR swizzle (1344 granules)
        const char* src = (const char*)(w2e + dx * 48 * 224);
#pragma unroll
        for (int j = 0; j < 6; j++) {
          int g = tid + j * 256;
          if (g < 1344) {
            int co = g / 28;
            int rem = g - co * 28;
            int dst = (co * 512 + rem * 16) ^ ((co & 7) << 4);
            *(int4v*)(wB + dst) = *(const int4v*)(src + g * 16);
          }
        }
      }
      __syncthreads();
#pragma unroll
      for (int kc = 0; kc < 7; kc++) {
        bf16x8 a0 = *(const bf16x8*)(wB + ((l15 * 512 + kl * 16 + kc * 64) ^ swz));
        bf16x8 a1 = *(const bf16x8*)(wB + ((8192 + l15 * 512 + kl * 16 + kc * 64) ^ swz));
        bf16x8 a2 = *(const bf16x8*)(wB + ((16384 + l15 * 512 + kl * 16 + kc * 64) ^ swz));
        int ba = g2[kc] ? (((or2 + dy2[kc]) * TCC + oc2 + dx) * (HID * 2) + ci2[kc] * 2) : 0;
        bf16x8 bv = *(const bf16x8*)(tsB + ba);
        acc2[0] = __builtin_amdgcn_mfma_f32_16x16x32_bf16(a0, bv, acc2[0], 0, 0, 0);
        acc2[1] = __builtin_amdgcn_mfma_f32_16x16x32_bf16(a1, bv, acc2[1], 0, 0, 0);
        acc2[2] = __builtin_amdgcn_mfma_f32_16x16x32_bf16(a2, bv, acc2[2], 0, 0, 0);
      }
    }
#pragma unroll
    for (int mt = 0; mt < 3; mt++) yacc[mt] += gv * acc2[mt];
  }

  // ---- store y (f32) ----
#pragma unroll
  for (int mt = 0; mt < 3; mt++) {
#pragma unroll
    for (int r = 0; r < 4; r++) {
      int co = mt * 16 + kl * 4 + r;
      if (co < CCH) {
        float v = (r == 0) ? yacc[mt].x : (r == 1) ? yacc[mt].y : (r == 2) ? yacc[mt].z : yacc[mt].w;
        y[xbase + ((size_t)co << 16) + (size_t)((ty0 + or2) * WW + tx0 + oc2)] = v;
      }
    }
  }
}

extern "C" void kernel_launch(void* const* d_in, const int* in_sizes, int n_in,
                              void* d_out, int out_size, void* d_ws, size_t ws_size,
                              hipStream_t stream) {
  const float* x      = (const float*)d_in[0];
  const float* time   = (const float*)d_in[1];
  const float* time_w = (const float*)d_in[2];
  const float* time_b = (const float*)d_in[3];
  const float* gw1    = (const float*)d_in[4];
  const float* gb1    = (const float*)d_in[5];
  const float* gw2    = (const float*)d_in[6];
  const float* gb2    = (const float*)d_in[7];
  const float* w1     = (const float*)d_in[8];
  const float* w2     = (const float*)d_in[9];
  float* out = (float*)d_out;
  float* ws  = (float*)d_ws;
  unsigned short* wt1 = (unsigned short*)((char*)d_ws + WT1_OFF);
  unsigned short* wt2 = (unsigned short*)((char*)d_ws + WT2_OFF);

  hipLaunchKernelGGL(pool_kernel, dim3(BB * CCH), dim3(256), 0, stream, x, ws);
  hipLaunchKernelGGL(gate_kernel, dim3(1), dim3(128), 0, stream,
                     time, time_w, time_b, gw1, gb1, gw2, gb2,
                     ws, out + (size_t)(out_size - 1));
  hipLaunchKernelGGL(wxform_kernel, dim3(756), dim3(256), 0, stream, w1, w2, wt1, wt2);
  hipLaunchKernelGGL(conv_kernel, dim3(1024, BB), dim3(256), 0, stream,
                     x, wt1, wt2, ws + WS_GATES, out);
}